// Round 13
// baseline (10217.521 us; speedup 1.0000x reference)
//
#include <hip/hip_runtime.h>
#include <cstdint>
#include <cstddef>

// Problem constants
#define K_ 512
#define T_ 32768
#define CHUNKS 128
#define LSTEP 256          // T_/CHUNKS

// workspace layout (bytes) -- total ~1.1 MB
#define OFF_E8    0ul        // 512*512 fp8 row-major
#define OFF_ET8   262144ul   // transposed fp8 (rows = E columns)
#define OFF_U     524288ul   // 128 x 512 f32
#define OFF_Z     786432ul   // 128 x 512 f32
#define OFF_GPART 1048576ul  // 32 f32
#define OFF_ALED  1048832ul  // 128 int
#define OFF_BLED  1049856ul  // 128 int
#define OFF_SSUM  1050880ul  // 128 f32
#define OFF_PARTS 1051904ul  // 128 double

#define FP8MAX 440.f

typedef float f32x2 __attribute__((ext_vector_type(2)));

// ---------------- prep: E8 = fp8(exp(tr)) row-major AND transposed ----------------
__global__ __launch_bounds__(512) void prep_k(const float* __restrict__ tr,
                                              uint8_t* __restrict__ E8,
                                              uint8_t* __restrict__ ET8) {
  int i = blockIdx.x;       // row
  int j = threadIdx.x;      // col
  float e = fminf(__expf(tr[i * 512 + j]), FP8MAX);
  int w = __builtin_amdgcn_cvt_pk_fp8_f32(e, e, 0, false);
  uint8_t b = (uint8_t)(w & 0xff);
  E8[i * 512 + j] = b;       // coalesced
  ET8[(size_t)j * 512 + i] = b;  // scattered (one-time, tiny)
}

// ---------------- gold score (exact f32, deterministic, 32 partials) ----------------
__global__ __launch_bounds__(1024) void gold_k(const float* __restrict__ obs,
                                               const int* __restrict__ tags,
                                               const float* __restrict__ tr,
                                               float* __restrict__ gpart) {
  __shared__ float red[1024];
  int i = blockIdx.x * 1024 + threadIdx.x;
  float s = 0.f;
  if (i < T_ - 1) {
    int cur = tags[i], nxt = tags[i + 1];
    s = tr[nxt * K_ + cur] + obs[(size_t)nxt * T_ + i];
  }
  red[threadIdx.x] = s;
  __syncthreads();
  for (int h = 512; h > 0; h >>= 1) {
    if ((int)threadIdx.x < h) red[threadIdx.x] += red[threadIdx.x + h];
    __syncthreads();
  }
  if (threadIdx.x == 0) gpart[blockIdx.x] = red[0];
}

// ---------------- uv: per-(chunk, dir) vector recurrence ----------------
// dir 0: u_c = P_c 1,  iterate t ascending:  v' = D_t E v       (exp AFTER dot)
// dir 1: z_c = P_c^T 1, iterate t descending: z' = E^T (D_t z)
//        (LDS holds y = D_t z: exp applied to the value BEFORE it is consumed;
//         initial y = D_{t_last} 1; final step stores raw z)
// Each thread owns one output row: its E (or E^T) row lives in 128 VGPRs (fp8),
// v in a 4KB LDS double buffer (uniform/broadcast reads, conflict-free).
// Exact power-of-2 renorm every 4 steps (integer ledger), all f32.
__global__ __launch_bounds__(512, 2)
void uv_k(const uint8_t* __restrict__ E8, const uint8_t* __restrict__ ET8,
          const float* __restrict__ obs,
          float* __restrict__ U, float* __restrict__ Z,
          int* __restrict__ Aled, int* __restrict__ Bled,
          float* __restrict__ Ssum) {
  __shared__ __align__(16) float vbuf[2][512];
  __shared__ float wred[8];

  const int r = threadIdx.x;
  const int wv = r >> 6, lane = r & 63;
  const int c = blockIdx.x >> 1;
  const int dir = blockIdx.x & 1;
  const int t0 = c * LSTEP;

  // my matrix row (fp8, 512 B = 32 x int4) -> 128 VGPRs, loaded once
  const uint8_t* Mrow = (dir ? ET8 : E8) + (size_t)r * 512;
  int4 er[32];
#pragma unroll
  for (int q = 0; q < 32; ++q) er[q] = ((const int4*)Mrow)[q];

  const float* orow = obs + (size_t)r * T_;

  if (dir == 0) vbuf[0][r] = 1.f;
  else          vbuf[0][r] = __expf(orow[t0 + LSTEP - 1]);
  __syncthreads();

  int led = 0;
  float fin = 0.f;

#pragma unroll 1
  for (int s = 0; s < LSTEP; ++s) {
    const float* vc = vbuf[s & 1];
    float* vn = vbuf[(s & 1) ^ 1];

    // obs scalar for this step's exp (consecutive steps share cachelines -> L1)
    float oload = 0.f;
    bool doexp;
    if (dir == 0) { oload = orow[t0 + s]; doexp = true; }
    else if (s < LSTEP - 1) { oload = orow[t0 + LSTEP - 2 - s]; doexp = true; }
    else doexp = false;

    float a0 = 0.f, a1 = 0.f, a2 = 0.f, a3 = 0.f;
#pragma unroll
    for (int q = 0; q < 32; ++q) {
      int4 w = er[q];
      const float4* vp = (const float4*)&vc[16 * q];
      float4 v0 = vp[0], v1 = vp[1], v2 = vp[2], v3 = vp[3];
      a0 += __builtin_amdgcn_cvt_f32_fp8(w.x, 0) * v0.x;
      a1 += __builtin_amdgcn_cvt_f32_fp8(w.x, 1) * v0.y;
      a2 += __builtin_amdgcn_cvt_f32_fp8(w.x, 2) * v0.z;
      a3 += __builtin_amdgcn_cvt_f32_fp8(w.x, 3) * v0.w;
      a0 += __builtin_amdgcn_cvt_f32_fp8(w.y, 0) * v1.x;
      a1 += __builtin_amdgcn_cvt_f32_fp8(w.y, 1) * v1.y;
      a2 += __builtin_amdgcn_cvt_f32_fp8(w.y, 2) * v1.z;
      a3 += __builtin_amdgcn_cvt_f32_fp8(w.y, 3) * v1.w;
      a0 += __builtin_amdgcn_cvt_f32_fp8(w.z, 0) * v2.x;
      a1 += __builtin_amdgcn_cvt_f32_fp8(w.z, 1) * v2.y;
      a2 += __builtin_amdgcn_cvt_f32_fp8(w.z, 2) * v2.z;
      a3 += __builtin_amdgcn_cvt_f32_fp8(w.z, 3) * v2.w;
      a0 += __builtin_amdgcn_cvt_f32_fp8(w.w, 0) * v3.x;
      a1 += __builtin_amdgcn_cvt_f32_fp8(w.w, 1) * v3.y;
      a2 += __builtin_amdgcn_cvt_f32_fp8(w.w, 2) * v3.z;
      a3 += __builtin_amdgcn_cvt_f32_fp8(w.w, 3) * v3.w;
    }
    float val = (a0 + a1) + (a2 + a3);
    if (doexp) val *= __expf(oload);

    if ((s & 3) == 3) {   // exact pow2 renorm, integer ledger
      float m = val;
#pragma unroll
      for (int off = 1; off < 64; off <<= 1) m = fmaxf(m, __shfl_xor(m, off, 64));
      if (lane == 0) wred[wv] = m;
      __syncthreads();
      float mm = fmaxf(fmaxf(fmaxf(wred[0], wred[1]), fmaxf(wred[2], wred[3])),
                       fmaxf(fmaxf(wred[4], wred[5]), fmaxf(wred[6], wred[7])));
      int e = (int)((__float_as_uint(mm) >> 23) & 255) - 127;
      e = min(max(e, -126), 126);
      led += e;
      val *= __uint_as_float((unsigned)(127 - e) << 23);
    }
    vn[r] = val;
    fin = val;
    __syncthreads();
  }

  // deterministic sum for s_c; store vectors + ledgers
  float sv = fin;
#pragma unroll
  for (int off = 1; off < 64; off <<= 1) sv += __shfl_xor(sv, off, 64);
  if (lane == 0) wred[wv] = sv;
  __syncthreads();
  if (dir == 0) {
    U[c * 512 + r] = fin;
    if (r == 0) {
      float t = 0.f;
      for (int q = 0; q < 8; ++q) t += wred[q];
      Ssum[c] = t;
      Aled[c] = led;
    }
  } else {
    Z[c * 512 + r] = fin;
    if (r == 0) Bled[c] = led;
  }
}

// ---------------- combine: parts[c] = ln(z_c . u_{c-1}) + ledgers - ln(s_c) ----------------
__global__ __launch_bounds__(64) void combine_k(const float* __restrict__ U,
                                                const float* __restrict__ Z,
                                                const int* __restrict__ Aled,
                                                const int* __restrict__ Bled,
                                                const float* __restrict__ Ssum,
                                                double* __restrict__ parts) {
  int cc = blockIdx.x + 1;           // 1..127
  int lane = threadIdx.x;
  float p = 0.f;
  for (int r = lane; r < 512; r += 64)
    p += Z[cc * 512 + r] * U[(cc - 1) * 512 + r];
#pragma unroll
  for (int off = 1; off < 64; off <<= 1) p += __shfl_xor(p, off, 64);
  if (lane == 0) {
    const double LN2 = 0.69314718055994530942;
    double term = log((double)p) + LN2 * (double)(Aled[cc - 1] + Bled[cc]);
    if (cc <= CHUNKS - 2)
      term -= log((double)Ssum[cc]) + LN2 * (double)Aled[cc];
    parts[cc] = term;
  }
}

// ---------------- final: out = forward - gold ----------------
__global__ __launch_bounds__(64) void final2_k(const double* __restrict__ parts,
                                               const float* __restrict__ gpart,
                                               float* __restrict__ outp) {
  if (threadIdx.x == 0) {
    double fwd = 0.0;
    for (int cc = 1; cc < CHUNKS; ++cc) fwd += parts[cc];
    double g = 0.0;
    for (int q = 0; q < 32; ++q) g += (double)gpart[q];
    outp[0] = (float)(fwd - g);
  }
}

extern "C" void kernel_launch(void* const* d_in, const int* in_sizes, int n_in,
                              void* d_out, int out_size, void* d_ws, size_t ws_size,
                              hipStream_t stream) {
  const float* obs = (const float*)d_in[0];   // (K, T) f32
  const int* tags = (const int*)d_in[1];      // (T,) i32
  const float* tr = (const float*)d_in[2];    // (K, K) f32
  float* out = (float*)d_out;

  uint8_t* ws = (uint8_t*)d_ws;
  uint8_t* E8 = ws + OFF_E8;
  uint8_t* ET8 = ws + OFF_ET8;
  float* U = (float*)(ws + OFF_U);
  float* Z = (float*)(ws + OFF_Z);
  float* gpart = (float*)(ws + OFF_GPART);
  int* Aled = (int*)(ws + OFF_ALED);
  int* Bled = (int*)(ws + OFF_BLED);
  float* Ssum = (float*)(ws + OFF_SSUM);
  double* parts = (double*)(ws + OFF_PARTS);

  hipLaunchKernelGGL(prep_k, dim3(512), dim3(512), 0, stream, tr, E8, ET8);
  hipLaunchKernelGGL(gold_k, dim3(32), dim3(1024), 0, stream, obs, tags, tr, gpart);
  hipLaunchKernelGGL(uv_k, dim3(CHUNKS * 2), dim3(512), 0, stream,
                     E8, ET8, obs, U, Z, Aled, Bled, Ssum);
  hipLaunchKernelGGL(combine_k, dim3(CHUNKS - 1), dim3(64), 0, stream,
                     U, Z, Aled, Bled, Ssum, parts);
  hipLaunchKernelGGL(final2_k, dim3(1), dim3(64), 0, stream, parts, gpart, out);
}

// Round 14
// 341.577 us; speedup vs baseline: 29.9128x; 29.9128x over previous
//
#include <hip/hip_runtime.h>
#include <cstdint>
#include <cstddef>

// Problem constants
#define K_ 512
#define T_ 32768
#define CHUNKS 2048
#define LSTEP 16           // T_/CHUNKS
#define NGRP 128           // CHUNKS/16 (16 chunk-columns per WG)

// workspace layout (bytes) -- total ~8.95 MB
#define OFF_E8    0ul        // 512*512 fp8 row-major
#define OFF_ET8   262144ul   // transposed fp8
#define OFF_U     524288ul   // 2048 x 512 f32 = 4 MB
#define OFF_Z     4718592ul  // 2048 x 512 f32 = 4 MB
#define OFF_GPART 8912896ul  // 32 f32
#define OFF_ALED  8913024ul  // 2048 int
#define OFF_BLED  8921216ul  // 2048 int
#define OFF_SSUM  8929408ul  // 2048 f32
#define OFF_PARTS 8937600ul  // 2048 double

#define FP8MAX 440.f

typedef float f32x4 __attribute__((ext_vector_type(4)));
typedef int i32x8 __attribute__((ext_vector_type(8)));

// 32B LDS fragment via 4x ds_read_b64 (conflict-free at stride 520; r4-r11 validated)
static __device__ __forceinline__ i32x8 lds_ld32(const uint8_t* p) {
  long long a = *(const long long*)p;
  long long b = *(const long long*)(p + 8);
  long long c = *(const long long*)(p + 16);
  long long d = *(const long long*)(p + 24);
  i32x8 r;
  r[0] = (int)a; r[1] = (int)(a >> 32);
  r[2] = (int)b; r[3] = (int)(b >> 32);
  r[4] = (int)c; r[5] = (int)(c >> 32);
  r[6] = (int)d; r[7] = (int)(d >> 32);
  return r;
}

// ---------------- prep: E8 = fp8(exp(tr)) row-major AND transposed ----------------
__global__ __launch_bounds__(512) void prep_k(const float* __restrict__ tr,
                                              uint8_t* __restrict__ E8,
                                              uint8_t* __restrict__ ET8) {
  int i = blockIdx.x;       // row
  int j = threadIdx.x;      // col
  float e = fminf(__expf(tr[i * 512 + j]), FP8MAX);
  int w = __builtin_amdgcn_cvt_pk_fp8_f32(e, e, 0, false);
  uint8_t b = (uint8_t)(w & 0xff);
  E8[i * 512 + j] = b;
  ET8[(size_t)j * 512 + i] = b;
}

// ---------------- gold score (exact f32, deterministic, 32 partials) ----------------
__global__ __launch_bounds__(1024) void gold_k(const float* __restrict__ obs,
                                               const int* __restrict__ tags,
                                               const float* __restrict__ tr,
                                               float* __restrict__ gpart) {
  __shared__ float red[1024];
  int i = blockIdx.x * 1024 + threadIdx.x;
  float s = 0.f;
  if (i < T_ - 1) {
    int cur = tags[i], nxt = tags[i + 1];
    s = tr[nxt * K_ + cur] + obs[(size_t)nxt * T_ + i];
  }
  red[threadIdx.x] = s;
  __syncthreads();
  for (int h = 512; h > 0; h >>= 1) {
    if ((int)threadIdx.x < h) red[threadIdx.x] += red[threadIdx.x + h];
    __syncthreads();
  }
  if (threadIdx.x == 0) gpart[blockIdx.x] = red[0];
}

// ---------------- uv: 16 chunk recurrences per WG via MFMA ----------------
// WG w: dir = w&1 (0: u_c = P_c 1 with E; 1: z_c = P_c^T 1 with E^T), grp = w>>1.
// Column c of the 512x16 batch = chunk grp*16+c, t-window [chunk*16, chunk*16+16).
// 8 waves; wave wv holds E rows 64wv..64wv+63 as MFMA A-fragments (128 VGPR,
// r4-r11 proven resident). V (512x16 fp8) double-buffered in LDS, col stride 520.
// Per step: acc = E*V (16 MFMA/wave, K=512), epilogue: val = acc * exp(obs[r,te]),
// exact per-COLUMN pow2 renorm (integer ledger), fp8 store. 16 serial steps.
// Last step: no renorm/fp8 -- write raw f32 u/z (+ Ssum for dir 0).
__global__ __launch_bounds__(512, 2)
void uv_k(const uint8_t* __restrict__ E8, const uint8_t* __restrict__ ET8,
          const float* __restrict__ obs,
          float* __restrict__ U, float* __restrict__ Z,
          int* __restrict__ Aled, int* __restrict__ Bled,
          float* __restrict__ Ssum) {
  __shared__ __align__(16) uint8_t Vb[2][16 * 520];   // 16640 B
  __shared__ float cred[8][16];                       // per-wave col max / col sum

  const int tid = threadIdx.x;
  const int wv = tid >> 6;
  const int lane = tid & 63;
  const int l15 = lane & 15;
  const int g = lane >> 4;
  const int dir = blockIdx.x & 1;
  const int grp = blockIdx.x >> 1;
  const int tbase = (grp * 16 + l15) * LSTEP;   // t0 of this lane's column

  // E (or E^T) fragments: lane holds A[row=64wv+16rt+l15][k=128kt+32g..+31]
  const uint8_t* M = dir ? ET8 : E8;
  i32x8 ef[4][4];
#pragma unroll
  for (int rt = 0; rt < 4; ++rt)
#pragma unroll
    for (int kt = 0; kt < 4; ++kt)
      ef[rt][kt] = *(const i32x8*)(M +
          ((64 * wv + 16 * rt + l15) * 512 + 128 * kt + 32 * g));

  // init V[0]
  if (dir == 0) {
    for (int i = tid; i < 16 * 520 / 4; i += 512)
      ((int*)Vb[0])[i] = 0x38383838;               // fp8 1.0 everywhere (pad unused)
  } else {
    const float* orow = obs + (size_t)tid * T_;    // row tid
#pragma unroll
    for (int c = 0; c < 16; ++c) {
      float e = fminf(__expf(orow[grp * 256 + c * LSTEP + (LSTEP - 1)]), FP8MAX);
      int w = __builtin_amdgcn_cvt_pk_fp8_f32(e, e, 0, false);
      Vb[0][c * 520 + tid] = (uint8_t)(w & 0xff);
    }
  }
  __syncthreads();

  int led = 0;                                     // ledger for column l15
  const f32x4 z4 = (f32x4){0.f, 0.f, 0.f, 0.f};
  const float* ob = obs + (size_t)(64 * wv + 4 * g) * T_;  // + (16rt+j)*T + te

  f32x4 acc[4];

#pragma unroll 1
  for (int s = 0; s < LSTEP; ++s) {
    const uint8_t* Vr = Vb[s & 1];
    uint8_t* Vw = Vb[(s & 1) ^ 1];

    // MFMA phase: acc[rt] = sum_kt E[rt][kt] x V[kt][l15-col]
    {
      const uint8_t* pb = Vr + l15 * 520 + 32 * g;
      i32x8 b = lds_ld32(pb);
#pragma unroll
      for (int rt = 0; rt < 4; ++rt)
        acc[rt] = __builtin_amdgcn_mfma_scale_f32_16x16x128_f8f6f4(
            ef[rt][0], b, z4, 0, 0, 0, 0x7f7f7f7f, 0, 0x7f7f7f7f);
#pragma unroll
      for (int kt = 1; kt < 4; ++kt) {
        b = lds_ld32(pb + 128 * kt);
#pragma unroll
        for (int rt = 0; rt < 4; ++rt)
          acc[rt] = __builtin_amdgcn_mfma_scale_f32_16x16x128_f8f6f4(
              ef[rt][kt], b, acc[rt], 0, 0, 0, 0x7f7f7f7f, 0, 0x7f7f7f7f);
      }
    }

    // epilogue: scale by exp(obs[row, te]) (except dir1 last step)
    const int te = dir ? (tbase + LSTEP - 2 - s) : (tbase + s);
    const bool doexp = (dir == 0) || (s < LSTEP - 1);
    float vmax = 0.f;
#pragma unroll
    for (int rt = 0; rt < 4; ++rt)
#pragma unroll
      for (int j = 0; j < 4; ++j) {
        float v = acc[rt][j];
        if (doexp) v *= __expf(ob[(16 * rt + j) * T_ + te]);
        acc[rt][j] = v;
        vmax = fmaxf(vmax, v);
      }

    if (s == LSTEP - 1) break;

    // exact per-column renorm: col max over g (shfl) then over waves (LDS)
    vmax = fmaxf(vmax, __shfl_xor(vmax, 16, 64));
    vmax = fmaxf(vmax, __shfl_xor(vmax, 32, 64));
    if (lane < 16) cred[wv][lane] = vmax;
    __syncthreads();
    float cm = cred[0][l15];
#pragma unroll
    for (int q = 1; q < 8; ++q) cm = fmaxf(cm, cred[q][l15]);
    int e = (int)((__float_as_uint(cm) >> 23) & 255) - 127;
    e = min(max(e, -120), 120);
    int sg = e - 7;                       // stored col max in [128,256)
    led += sg;
    float sc = __uint_as_float((unsigned)(127 - sg) << 23);

#pragma unroll
    for (int rt = 0; rt < 4; ++rt) {
      float v0 = acc[rt][0] * sc, v1 = acc[rt][1] * sc;
      float v2 = acc[rt][2] * sc, v3 = acc[rt][3] * sc;
      int w32 = __builtin_amdgcn_cvt_pk_fp8_f32(v0, v1, 0, false);
      w32 = __builtin_amdgcn_cvt_pk_fp8_f32(v2, v3, w32, true);
      *(int*)(Vw + l15 * 520 + 64 * wv + 16 * rt + 4 * g) = w32;
    }
    __syncthreads();
  }

  // final store: raw f32 vectors (chunk = grp*16 + l15), ledgers, Ssum (dir 0)
  float* dst = (dir ? Z : U) + (size_t)(grp * 16 + l15) * 512 + 64 * wv + 4 * g;
#pragma unroll
  for (int rt = 0; rt < 4; ++rt) {
    float4 o4;
    o4.x = acc[rt][0]; o4.y = acc[rt][1]; o4.z = acc[rt][2]; o4.w = acc[rt][3];
    *(float4*)(dst + 16 * rt) = o4;
  }

  if (dir == 0) {
    float ssum = 0.f;
#pragma unroll
    for (int rt = 0; rt < 4; ++rt)
#pragma unroll
      for (int j = 0; j < 4; ++j) ssum += acc[rt][j];
    ssum += __shfl_xor(ssum, 16, 64);
    ssum += __shfl_xor(ssum, 32, 64);
    if (lane < 16) cred[wv][lane] = ssum;
    __syncthreads();
    if (wv == 0 && lane < 16) {
      float t = 0.f;
#pragma unroll
      for (int q = 0; q < 8; ++q) t += cred[q][lane];
      Ssum[grp * 16 + lane] = t;
      Aled[grp * 16 + lane] = led;
    }
  } else {
    if (wv == 0 && lane < 16) Bled[grp * 16 + lane] = led;
  }
}

// ---------------- combine: parts[cc] = ln(z_cc . u_{cc-1}) + ledgers - ln(s_cc) ----------------
__global__ __launch_bounds__(64) void combine_k(const float* __restrict__ U,
                                                const float* __restrict__ Z,
                                                const int* __restrict__ Aled,
                                                const int* __restrict__ Bled,
                                                const float* __restrict__ Ssum,
                                                double* __restrict__ parts) {
  int cc = blockIdx.x + 1;           // 1..CHUNKS-1
  int lane = threadIdx.x;
  float p = 0.f;
  for (int r = lane; r < 512; r += 64)
    p += Z[(size_t)cc * 512 + r] * U[(size_t)(cc - 1) * 512 + r];
#pragma unroll
  for (int off = 1; off < 64; off <<= 1) p += __shfl_xor(p, off, 64);
  if (lane == 0) {
    const double LN2 = 0.69314718055994530942;
    double term = log((double)p) + LN2 * (double)(Aled[cc - 1] + Bled[cc]);
    if (cc <= CHUNKS - 2)
      term -= log((double)Ssum[cc]) + LN2 * (double)Aled[cc];
    parts[cc] = term;
  }
}

// ---------------- final: out = sum(parts) - gold ----------------
__global__ __launch_bounds__(256) void final2_k(const double* __restrict__ parts,
                                                const float* __restrict__ gpart,
                                                float* __restrict__ outp) {
  __shared__ double red[256];
  double s = 0.0;
  for (int i = 1 + (int)threadIdx.x; i < CHUNKS; i += 256) s += parts[i];
  red[threadIdx.x] = s;
  __syncthreads();
  for (int h = 128; h > 0; h >>= 1) {
    if ((int)threadIdx.x < h) red[threadIdx.x] += red[threadIdx.x + h];
    __syncthreads();
  }
  if (threadIdx.x == 0) {
    double g = 0.0;
    for (int q = 0; q < 32; ++q) g += (double)gpart[q];
    outp[0] = (float)(red[0] - g);
  }
}

extern "C" void kernel_launch(void* const* d_in, const int* in_sizes, int n_in,
                              void* d_out, int out_size, void* d_ws, size_t ws_size,
                              hipStream_t stream) {
  const float* obs = (const float*)d_in[0];   // (K, T) f32
  const int* tags = (const int*)d_in[1];      // (T,) i32
  const float* tr = (const float*)d_in[2];    // (K, K) f32
  float* out = (float*)d_out;

  uint8_t* ws = (uint8_t*)d_ws;
  uint8_t* E8 = ws + OFF_E8;
  uint8_t* ET8 = ws + OFF_ET8;
  float* U = (float*)(ws + OFF_U);
  float* Z = (float*)(ws + OFF_Z);
  float* gpart = (float*)(ws + OFF_GPART);
  int* Aled = (int*)(ws + OFF_ALED);
  int* Bled = (int*)(ws + OFF_BLED);
  float* Ssum = (float*)(ws + OFF_SSUM);
  double* parts = (double*)(ws + OFF_PARTS);

  hipLaunchKernelGGL(prep_k, dim3(512), dim3(512), 0, stream, tr, E8, ET8);
  hipLaunchKernelGGL(gold_k, dim3(32), dim3(1024), 0, stream, obs, tags, tr, gpart);
  hipLaunchKernelGGL(uv_k, dim3(NGRP * 2), dim3(512), 0, stream,
                     E8, ET8, obs, U, Z, Aled, Bled, Ssum);
  hipLaunchKernelGGL(combine_k, dim3(CHUNKS - 1), dim3(64), 0, stream,
                     U, Z, Aled, Bled, Ssum, parts);
  hipLaunchKernelGGL(final2_k, dim3(1), dim3(256), 0, stream, parts, gpart, out);
}

// Round 16
// 77.929 us; speedup vs baseline: 131.1131x; 4.3832x over previous
//
#include <hip/hip_runtime.h>
#include <cstdint>
#include <cstddef>

// Problem constants
#define K_ 512
#define T_ 32768
#define CHUNKS 2048
#define LSTEP 16           // T_/CHUNKS
#define NGRP 128           // CHUNKS/16 (16 chunk-columns per WG)

// workspace layout (bytes) -- total ~25.7 MB
#define OFF_E8    0ul        // 512*512 fp8 row-major
#define OFF_ET8   262144ul   // transposed fp8
#define OFF_U     524288ul   // 2048 x 512 f32 = 4 MB
#define OFF_Z     4718592ul  // 2048 x 512 f32 = 4 MB
#define OFF_GPART 8912896ul  // 32 f32
#define OFF_ALED  8913024ul  // 2048 int
#define OFF_BLED  8921216ul  // 2048 int
#define OFF_SSUM  8929408ul  // 2048 f32
#define OFF_PARTS 8937600ul  // 2048 double (end 8953984)
#define OFF_EXPT  8953984ul  // expT[t][k] fp8: 32768*512 = 16 MB (end 25731200)

#define FP8MAX 440.f

typedef float f32x4 __attribute__((ext_vector_type(4)));
typedef int i32x8 __attribute__((ext_vector_type(8)));

// 32B LDS fragment via 4x ds_read_b64 (conflict-free at stride 520; r4-r14 validated)
static __device__ __forceinline__ i32x8 lds_ld32(const uint8_t* p) {
  long long a = *(const long long*)p;
  long long b = *(const long long*)(p + 8);
  long long c = *(const long long*)(p + 16);
  long long d = *(const long long*)(p + 24);
  i32x8 r;
  r[0] = (int)a; r[1] = (int)(a >> 32);
  r[2] = (int)b; r[3] = (int)(b >> 32);
  r[4] = (int)c; r[5] = (int)(c >> 32);
  r[6] = (int)d; r[7] = (int)(d >> 32);
  return r;
}

// ---------------- prep: E8 = fp8(exp(tr)) row-major AND transposed ----------------
__global__ __launch_bounds__(512) void prep_k(const float* __restrict__ tr,
                                              uint8_t* __restrict__ E8,
                                              uint8_t* __restrict__ ET8) {
  int i = blockIdx.x;       // row
  int j = threadIdx.x;      // col
  float e = fminf(__expf(tr[i * 512 + j]), FP8MAX);
  int w = __builtin_amdgcn_cvt_pk_fp8_f32(e, e, 0, false);
  uint8_t b = (uint8_t)(w & 0xff);
  E8[i * 512 + j] = b;
  ET8[(size_t)j * 512 + i] = b;
}

// ---------------- texp: expT[t][k] = fp8(exp(obs[k][t])), 64x64 LDS tile ----------------
__global__ __launch_bounds__(256) void texp_k(const float* __restrict__ obs,
                                              uint8_t* __restrict__ expT) {
  __shared__ uint8_t tile[64][68];     // t-major in tile, padded (4B-aligned rows)
  const int t0 = (blockIdx.x & 511) * 64;   // T/64 = 512
  const int k0 = (blockIdx.x >> 9) * 64;    // K/64 = 8
  const int tx = threadIdx.x & 63;          // t offset (coalesced read dim)
  const int ky = threadIdx.x >> 6;          // 0..3
#pragma unroll
  for (int q = 0; q < 16; ++q) {
    int k = ky * 16 + q;                    // 0..63
    float v = obs[(size_t)(k0 + k) * T_ + t0 + tx];
    float e = fminf(__expf(v), FP8MAX);
    int w = __builtin_amdgcn_cvt_pk_fp8_f32(e, e, 0, false);
    tile[tx][k] = (uint8_t)(w & 0xff);
  }
  __syncthreads();
  // write out: thread -> (t-row ty, 16-byte k segment)
  const int ty = threadIdx.x >> 2;          // 0..63
  const int kq = (threadIdx.x & 3) * 16;    // 0,16,32,48
  const uint8_t* src = &tile[ty][kq];
  uint4 o;
  o.x = *(const unsigned*)(src + 0);
  o.y = *(const unsigned*)(src + 4);
  o.z = *(const unsigned*)(src + 8);
  o.w = *(const unsigned*)(src + 12);
  *(uint4*)(expT + (size_t)(t0 + ty) * 512 + k0 + kq) = o;
}

// ---------------- gold score (exact f32, deterministic, 32 partials) ----------------
__global__ __launch_bounds__(1024) void gold_k(const float* __restrict__ obs,
                                               const int* __restrict__ tags,
                                               const float* __restrict__ tr,
                                               float* __restrict__ gpart) {
  __shared__ float red[1024];
  int i = blockIdx.x * 1024 + threadIdx.x;
  float s = 0.f;
  if (i < T_ - 1) {
    int cur = tags[i], nxt = tags[i + 1];
    s = tr[nxt * K_ + cur] + obs[(size_t)nxt * T_ + i];
  }
  red[threadIdx.x] = s;
  __syncthreads();
  for (int h = 512; h > 0; h >>= 1) {
    if ((int)threadIdx.x < h) red[threadIdx.x] += red[threadIdx.x + h];
    __syncthreads();
  }
  if (threadIdx.x == 0) gpart[blockIdx.x] = red[0];
}

// ---------------- uv: 16 chunk recurrences per WG via MFMA ----------------
// Round-14 structure (validated absmax 0.0) with the epilogue exp factors from
// pre-transposed fp8 expT: 4 aligned u32 loads/thread/step (row-contiguous,
// each wave touches 16 fully-used cachelines) instead of 16 scalar 4B loads at
// 128KB stride (r14's 8x over-fetch: 1.05 GB -> L2 thrash). cvt_f32_fp8
// byte-selects hand-unrolled with literal constants (r15 compile fix).
__global__ __launch_bounds__(512, 2)
void uv_k(const uint8_t* __restrict__ E8, const uint8_t* __restrict__ ET8,
          const uint8_t* __restrict__ expT,
          float* __restrict__ U, float* __restrict__ Z,
          int* __restrict__ Aled, int* __restrict__ Bled,
          float* __restrict__ Ssum) {
  __shared__ __align__(16) uint8_t Vb[2][16 * 520];   // 16640 B
  __shared__ float cred[8][16];                       // per-wave col max / col sum

  const int tid = threadIdx.x;
  const int wv = tid >> 6;
  const int lane = tid & 63;
  const int l15 = lane & 15;
  const int g = lane >> 4;
  const int dir = blockIdx.x & 1;
  const int grp = blockIdx.x >> 1;
  const int tbase = (grp * 16 + l15) * LSTEP;   // t0 of this lane's column

  // E (or E^T) fragments: lane holds A[row=64wv+16rt+l15][k=128kt+32g..+31]
  const uint8_t* M = dir ? ET8 : E8;
  i32x8 ef[4][4];
#pragma unroll
  for (int rt = 0; rt < 4; ++rt)
#pragma unroll
    for (int kt = 0; kt < 4; ++kt)
      ef[rt][kt] = *(const i32x8*)(M +
          ((64 * wv + 16 * rt + l15) * 512 + 128 * kt + 32 * g));

  // init V[0]
  if (dir == 0) {
    for (int i = tid; i < 16 * 520 / 4; i += 512)
      ((int*)Vb[0])[i] = 0x38383838;               // fp8 1.0 everywhere (pad unused)
  } else {
#pragma unroll
    for (int c = 0; c < 16; ++c)
      Vb[0][c * 520 + tid] =
          expT[(size_t)(grp * 256 + c * LSTEP + (LSTEP - 1)) * 512 + tid];
  }
  __syncthreads();

  int led = 0;                                     // ledger for column l15
  const f32x4 z4 = (f32x4){0.f, 0.f, 0.f, 0.f};

  f32x4 acc[4];

#pragma unroll 1
  for (int s = 0; s < LSTEP; ++s) {
    const uint8_t* Vr = Vb[s & 1];
    uint8_t* Vw = Vb[(s & 1) ^ 1];

    // issue this step's exp-factor loads FIRST (independent of LDS state;
    // latency hides under the MFMA chain below)
    const int te = dir ? (tbase + LSTEP - 2 - s) : (tbase + s);
    const bool doexp = (dir == 0) || (s < LSTEP - 1);
    unsigned ew[4];
    if (doexp) {
      const uint8_t* ep = expT + (size_t)te * 512 + 64 * wv + 4 * g;
#pragma unroll
      for (int rt = 0; rt < 4; ++rt) ew[rt] = *(const unsigned*)(ep + 16 * rt);
    }

    // MFMA phase: acc[rt] = sum_kt E[rt][kt] x V[kt][l15-col]
    {
      const uint8_t* pb = Vr + l15 * 520 + 32 * g;
      i32x8 b = lds_ld32(pb);
#pragma unroll
      for (int rt = 0; rt < 4; ++rt)
        acc[rt] = __builtin_amdgcn_mfma_scale_f32_16x16x128_f8f6f4(
            ef[rt][0], b, z4, 0, 0, 0, 0x7f7f7f7f, 0, 0x7f7f7f7f);
#pragma unroll
      for (int kt = 1; kt < 4; ++kt) {
        b = lds_ld32(pb + 128 * kt);
#pragma unroll
        for (int rt = 0; rt < 4; ++rt)
          acc[rt] = __builtin_amdgcn_mfma_scale_f32_16x16x128_f8f6f4(
              ef[rt][kt], b, acc[rt], 0, 0, 0, 0x7f7f7f7f, 0, 0x7f7f7f7f);
      }
    }

    // epilogue: scale by fp8 exp factor (except dir1 last step);
    // byte-selects are literal constants (hand-unrolled)
    float vmax = 0.f;
#pragma unroll
    for (int rt = 0; rt < 4; ++rt) {
      float v0 = acc[rt][0], v1 = acc[rt][1], v2 = acc[rt][2], v3 = acc[rt][3];
      if (doexp) {
        int w = (int)ew[rt];
        v0 *= __builtin_amdgcn_cvt_f32_fp8(w, 0);
        v1 *= __builtin_amdgcn_cvt_f32_fp8(w, 1);
        v2 *= __builtin_amdgcn_cvt_f32_fp8(w, 2);
        v3 *= __builtin_amdgcn_cvt_f32_fp8(w, 3);
      }
      acc[rt][0] = v0; acc[rt][1] = v1; acc[rt][2] = v2; acc[rt][3] = v3;
      vmax = fmaxf(vmax, fmaxf(fmaxf(v0, v1), fmaxf(v2, v3)));
    }

    if (s == LSTEP - 1) break;

    // exact per-column renorm: col max over g (shfl) then over waves (LDS)
    vmax = fmaxf(vmax, __shfl_xor(vmax, 16, 64));
    vmax = fmaxf(vmax, __shfl_xor(vmax, 32, 64));
    if (lane < 16) cred[wv][lane] = vmax;
    __syncthreads();
    float cm = cred[0][l15];
#pragma unroll
    for (int q = 1; q < 8; ++q) cm = fmaxf(cm, cred[q][l15]);
    int e = (int)((__float_as_uint(cm) >> 23) & 255) - 127;
    e = min(max(e, -120), 120);
    int sg = e - 7;                       // stored col max in [128,256)
    led += sg;
    float sc = __uint_as_float((unsigned)(127 - sg) << 23);

#pragma unroll
    for (int rt = 0; rt < 4; ++rt) {
      float v0 = acc[rt][0] * sc, v1 = acc[rt][1] * sc;
      float v2 = acc[rt][2] * sc, v3 = acc[rt][3] * sc;
      int w32 = __builtin_amdgcn_cvt_pk_fp8_f32(v0, v1, 0, false);
      w32 = __builtin_amdgcn_cvt_pk_fp8_f32(v2, v3, w32, true);
      *(int*)(Vw + l15 * 520 + 64 * wv + 16 * rt + 4 * g) = w32;
    }
    __syncthreads();
  }

  // final store: raw f32 vectors (chunk = grp*16 + l15), ledgers, Ssum (dir 0)
  float* dst = (dir ? Z : U) + (size_t)(grp * 16 + l15) * 512 + 64 * wv + 4 * g;
#pragma unroll
  for (int rt = 0; rt < 4; ++rt) {
    float4 o4;
    o4.x = acc[rt][0]; o4.y = acc[rt][1]; o4.z = acc[rt][2]; o4.w = acc[rt][3];
    *(float4*)(dst + 16 * rt) = o4;
  }

  if (dir == 0) {
    float ssum = 0.f;
#pragma unroll
    for (int rt = 0; rt < 4; ++rt)
#pragma unroll
      for (int j = 0; j < 4; ++j) ssum += acc[rt][j];
    ssum += __shfl_xor(ssum, 16, 64);
    ssum += __shfl_xor(ssum, 32, 64);
    if (lane < 16) cred[wv][lane] = ssum;
    __syncthreads();
    if (wv == 0 && lane < 16) {
      float t = 0.f;
#pragma unroll
      for (int q = 0; q < 8; ++q) t += cred[q][lane];
      Ssum[grp * 16 + lane] = t;
      Aled[grp * 16 + lane] = led;
    }
  } else {
    if (wv == 0 && lane < 16) Bled[grp * 16 + lane] = led;
  }
}

// ---------------- combine: parts[cc] = ln(z_cc . u_{cc-1}) + ledgers - ln(s_cc) ----------------
__global__ __launch_bounds__(64) void combine_k(const float* __restrict__ U,
                                                const float* __restrict__ Z,
                                                const int* __restrict__ Aled,
                                                const int* __restrict__ Bled,
                                                const float* __restrict__ Ssum,
                                                double* __restrict__ parts) {
  int cc = blockIdx.x + 1;           // 1..CHUNKS-1
  int lane = threadIdx.x;
  float p = 0.f;
  for (int r = lane; r < 512; r += 64)
    p += Z[(size_t)cc * 512 + r] * U[(size_t)(cc - 1) * 512 + r];
#pragma unroll
  for (int off = 1; off < 64; off <<= 1) p += __shfl_xor(p, off, 64);
  if (lane == 0) {
    const double LN2 = 0.69314718055994530942;
    double term = log((double)p) + LN2 * (double)(Aled[cc - 1] + Bled[cc]);
    if (cc <= CHUNKS - 2)
      term -= log((double)Ssum[cc]) + LN2 * (double)Aled[cc];
    parts[cc] = term;
  }
}

// ---------------- final: out = sum(parts) - gold ----------------
__global__ __launch_bounds__(256) void final2_k(const double* __restrict__ parts,
                                                const float* __restrict__ gpart,
                                                float* __restrict__ outp) {
  __shared__ double red[256];
  double s = 0.0;
  for (int i = 1 + (int)threadIdx.x; i < CHUNKS; i += 256) s += parts[i];
  red[threadIdx.x] = s;
  __syncthreads();
  for (int h = 128; h > 0; h >>= 1) {
    if ((int)threadIdx.x < h) red[threadIdx.x] += red[threadIdx.x + h];
    __syncthreads();
  }
  if (threadIdx.x == 0) {
    double g = 0.0;
    for (int q = 0; q < 32; ++q) g += (double)gpart[q];
    outp[0] = (float)(red[0] - g);
  }
}

extern "C" void kernel_launch(void* const* d_in, const int* in_sizes, int n_in,
                              void* d_out, int out_size, void* d_ws, size_t ws_size,
                              hipStream_t stream) {
  const float* obs = (const float*)d_in[0];   // (K, T) f32
  const int* tags = (const int*)d_in[1];      // (T,) i32
  const float* tr = (const float*)d_in[2];    // (K, K) f32
  float* out = (float*)d_out;

  uint8_t* ws = (uint8_t*)d_ws;
  uint8_t* E8 = ws + OFF_E8;
  uint8_t* ET8 = ws + OFF_ET8;
  float* U = (float*)(ws + OFF_U);
  float* Z = (float*)(ws + OFF_Z);
  float* gpart = (float*)(ws + OFF_GPART);
  int* Aled = (int*)(ws + OFF_ALED);
  int* Bled = (int*)(ws + OFF_BLED);
  float* Ssum = (float*)(ws + OFF_SSUM);
  double* parts = (double*)(ws + OFF_PARTS);
  uint8_t* expT = ws + OFF_EXPT;

  hipLaunchKernelGGL(prep_k, dim3(512), dim3(512), 0, stream, tr, E8, ET8);
  hipLaunchKernelGGL(texp_k, dim3(512 * 8), dim3(256), 0, stream, obs, expT);
  hipLaunchKernelGGL(gold_k, dim3(32), dim3(1024), 0, stream, obs, tags, tr, gpart);
  hipLaunchKernelGGL(uv_k, dim3(NGRP * 2), dim3(512), 0, stream,
                     E8, ET8, expT, U, Z, Aled, Bled, Ssum);
  hipLaunchKernelGGL(combine_k, dim3(CHUNKS - 1), dim3(64), 0, stream,
                     U, Z, Aled, Bled, Ssum, parts);
  hipLaunchKernelGGL(final2_k, dim3(1), dim3(256), 0, stream, parts, gpart, out);
}